// Round 1
// baseline (5261.758 us; speedup 1.0000x reference)
//
#include <hip/hip_runtime.h>
#include <math.h>

#define COUT 192

// ---------------- weight prep: cw[((c*25+k)*192+o)*2] = {m_w[o,c,k], -2*w_w[o,c,k]} ----------------
template<int CIN>
__global__ void prep_weights(const float* __restrict__ m_w, const float* __restrict__ w_w,
                             float* __restrict__ cw) {
    int idx = blockIdx.x * 256 + threadIdx.x;
    const int total = CIN * 25 * COUT;
    if (idx >= total) return;
    int o = idx % COUT;
    int k = (idx / COUT) % 25;
    int c = idx / (COUT * 25);
    float m = m_w[(o * CIN + c) * 25 + k];
    float w = w_w[(o * CIN + c) * 25 + k];
    cw[(size_t)idx * 2 + 0] = m;
    cw[(size_t)idx * 2 + 1] = -2.0f * w;
}

// ---------------- fused INRF layer ----------------
// Block: 256 threads. Owns (image b, R output rows, all COUT channels).
// Per input channel c: stage haloed window in LDS, compute s=tanh((v-center)*12.5) once
// into LDS (shared by all output channels), then FMA against interleaved weights.
template<int H, int W, int CIN, int R, bool POOL>
__global__ __launch_bounds__(256) void inrf_kernel(
    const float* __restrict__ x, const float* __restrict__ cw,
    const float* __restrict__ bias, float* __restrict__ out)
{
    constexpr int TP = R * W;          // positions per block tile
    constexpr int NG = 256 / TP;       // thread groups (channel splits)
    constexpr int CHG = COUT / NG;     // channels per group
    constexpr int WR = R + 4, WC = W + 4;

    __shared__ float win[WR][WC];
    __shared__ float sv[25][TP];

    const int tid = threadIdx.x;
    const int tilesPerImg = H / R;
    const int b  = blockIdx.x / tilesPerImg;
    const int r0 = (blockIdx.x % tilesPerImg) * R;

    const int p  = tid % TP;           // position within tile
    const int og = tid / TP;           // channel group
    const int pr = p / W, pc = p % W;
    const int obase = og * CHG;

    float acc[CHG];
    #pragma unroll
    for (int j = 0; j < CHG; ++j) acc[j] = 0.f;

    for (int c = 0; c < CIN; ++c) {
        // ---- stage window (zero-padded halo) ----
        const float* xc = x + (size_t)(b * CIN + c) * H * W;
        for (int i = tid; i < WR * WC; i += 256) {
            int row = i / WC, col = i % WC;
            int gr = r0 + row - 2, gc = col - 2;
            float v = 0.f;
            if (gr >= 0 && gr < H && gc >= 0 && gc < W) v = xc[gr * W + gc];
            win[row][col] = v;
        }
        __syncthreads();
        // ---- s values, computed once, shared across output channels ----
        for (int i = tid; i < 25 * TP; i += 256) {
            int k = i / TP, pp = i % TP;
            int ppr = pp / W, ppc = pp % W;
            int ky = k / 5, kx = k % 5;
            float v   = win[ppr + ky][ppc + kx];
            float cen = win[ppr + 2][ppc + 2];
            sv[k][pp] = tanhf((v - cen) * 12.5f);
        }
        __syncthreads();
        // ---- contraction: acc[o] += m*v + (-2w)*s ----
        const float* wcp = cw + (size_t)c * 25 * COUT * 2 + obase * 2;
        #pragma unroll 5
        for (int k = 0; k < 25; ++k) {
            int ky = k / 5, kx = k % 5;
            float vv  = win[pr + ky][pc + kx];
            float s2v = sv[k][p];
            const float4* wp = (const float4*)(wcp + (size_t)k * COUT * 2);
            #pragma unroll
            for (int j2 = 0; j2 < CHG / 2; ++j2) {
                float4 q = wp[j2];
                acc[2*j2]   = fmaf(q.x, vv,  acc[2*j2]);
                acc[2*j2]   = fmaf(q.y, s2v, acc[2*j2]);
                acc[2*j2+1] = fmaf(q.z, vv,  acc[2*j2+1]);
                acc[2*j2+1] = fmaf(q.w, s2v, acc[2*j2+1]);
            }
        }
        __syncthreads();   // protect win/sv before next-channel overwrite
    }

    if constexpr (POOL) {
        // TP == 64: each group is exactly one wave; 2x2 maxpool via shfl_xor.
        #pragma unroll
        for (int j = 0; j < CHG; ++j) {
            int o = obase + j;
            float v = acc[j] + bias[o];
            v = fmaxf(v, __shfl_xor(v, 1));    // col pair
            v = fmaxf(v, __shfl_xor(v, 32));   // row pair
            if (pr == 0 && (pc & 1) == 0) {
                out[(((size_t)b * COUT + o) * (H/2) + (r0 >> 1)) * (W/2) + (pc >> 1)] = v;
            }
        }
    } else {
        #pragma unroll
        for (int j = 0; j < CHG; ++j) {
            int o = obase + j;
            out[(((size_t)b * COUT + o) * H + (r0 + pr)) * W + pc] = acc[j] + bias[o];
        }
    }
}

// ---------------- 2x2 maxpool (x01 -> x03) ----------------
__global__ void maxpool2_kernel(const float* __restrict__ in, float* __restrict__ out,
                                int Hout, int Wout, int total) {
    int idx = blockIdx.x * 256 + threadIdx.x;
    if (idx >= total) return;
    int w  = idx % Wout;
    int h  = (idx / Wout) % Hout;
    int bc = idx / (Wout * Hout);
    const float* p = in + ((size_t)bc * Hout * 2 + h * 2) * (Wout * 2) + w * 2;
    int s = Wout * 2;
    out[idx] = fmaxf(fmaxf(p[0], p[1]), fmaxf(p[s], p[s + 1]));
}

// ---------------- avgpool8 + FC ----------------
__global__ void avgfc_kernel(const float* __restrict__ x04, const float* __restrict__ fc_w,
                             const float* __restrict__ fc_b, float* __restrict__ logits) {
    __shared__ float feat[COUT];
    int b = blockIdx.x;
    int t = threadIdx.x;
    if (t < COUT) {
        const float* p = x04 + ((size_t)b * COUT + t) * 64;
        float s = 0.f;
        #pragma unroll
        for (int i = 0; i < 64; ++i) s += p[i];
        feat[t] = s * (1.f / 64.f);
    }
    __syncthreads();
    if (t < 10) {
        float s = fc_b[t];
        #pragma unroll 8
        for (int c = 0; c < COUT; ++c) s = fmaf(fc_w[t * COUT + c], feat[c], s);
        logits[(size_t)b * 10 + t] = s;
    }
}

extern "C" void kernel_launch(void* const* d_in, const int* in_sizes, int n_in,
                              void* d_out, int out_size, void* d_ws, size_t ws_size,
                              hipStream_t stream) {
    const float* x    = (const float*)d_in[0];
    const float* m1_w = (const float*)d_in[1];
    const float* m1_b = (const float*)d_in[2];
    const float* w1_w = (const float*)d_in[3];
    const float* m2_w = (const float*)d_in[4];
    const float* m2_b = (const float*)d_in[5];
    const float* w2_w = (const float*)d_in[6];
    const float* m3_w = (const float*)d_in[7];
    const float* m3_b = (const float*)d_in[8];
    const float* w3_w = (const float*)d_in[9];
    const float* fc_w = (const float*)d_in[10];
    const float* fc_b = (const float*)d_in[11];

    float* out = (float*)d_out;
    float* ws  = (float*)d_ws;

    // d_out layout: [logits(640) | x00(64*192*16*16) | x01(64*192*16*16)]
    float* logits = out;
    float* x00 = out + 640;
    float* x01 = out + 640 + 3145728;

    // ws layout (floats)
    float* cw1 = ws;                       //    28,800
    float* cw2 = ws + 28800;               // 1,843,200
    float* cw3 = ws + 1872000;             // 1,843,200
    float* x03 = ws + 3715200;             //   786,432
    float* x04 = ws + 4501632;             //   786,432  (total 21.2 MB)

    prep_weights<3>  <<<(3 * 25 * COUT + 255) / 256,   256, 0, stream>>>(m1_w, w1_w, cw1);
    prep_weights<192><<<(192 * 25 * COUT + 255) / 256, 256, 0, stream>>>(m2_w, w2_w, cw2);
    prep_weights<192><<<(192 * 25 * COUT + 255) / 256, 256, 0, stream>>>(m3_w, w3_w, cw3);

    // Layer 1: INRF(3->192, 32x32) fused with 2x2 maxpool -> x00 [64,192,16,16]
    inrf_kernel<32, 32, 3, 2, true><<<64 * 16, 256, 0, stream>>>(x, cw1, m1_b, x00);
    // Layer 2: INRF(192->192, 16x16) -> x01 [64,192,16,16]
    inrf_kernel<16, 16, 192, 2, false><<<64 * 8, 256, 0, stream>>>(x00, cw2, m2_b, x01);
    // maxpool -> x03 [64,192,8,8]
    maxpool2_kernel<<<(786432 + 255) / 256, 256, 0, stream>>>(x01, x03, 8, 8, 786432);
    // Layer 3: INRF(192->192, 8x8) -> x04
    inrf_kernel<8, 8, 192, 2, false><<<64 * 4, 256, 0, stream>>>(x03, cw3, m3_b, x04);
    // avgpool8 + FC -> logits
    avgfc_kernel<<<64, 256, 0, stream>>>(x04, fc_w, fc_b, logits);
}

// Round 2
// 333.127 us; speedup vs baseline: 15.7950x; 15.7950x over previous
//
#include <hip/hip_runtime.h>
#include <math.h>

#define COUT 192
#define NF 12

typedef __bf16 bf16_8 __attribute__((ext_vector_type(8)));
typedef float  f32x4  __attribute__((ext_vector_type(4)));

__device__ __forceinline__ float fast_tanh125(float d) {
    // tanh(12.5*d) = 1 - 2/(exp2(36.0674*d)+1)
    float e = __builtin_amdgcn_exp2f(d * 36.06737602222409f);
    return 1.0f - 2.0f * __builtin_amdgcn_rcpf(e + 1.0f);
}

// ---- weight prep: Bp[(cc*NF+nf)*64 + lane][8] bf16, cc=c*2+t, k=(lane>>4)*8+e, n=nf*16+(lane&15)
// t=0 -> m_w, t=1 -> -2*w_w; k>=25 padded with 0 (makes A pad values don't-care).
template<int CIN>
__global__ void prep_w(const float* __restrict__ m_w, const float* __restrict__ w_w,
                       __bf16* __restrict__ Bp) {
    int idx = blockIdx.x * 256 + threadIdx.x;
    const int total = CIN * 2 * NF * 64;
    if (idx >= total) return;
    int lane = idx & 63;
    int nf = (idx >> 6) % NF;
    int cc = idx / (NF * 64);
    int t = cc & 1, c = cc >> 1;
    int n = nf * 16 + (lane & 15);
    int k0 = (lane >> 4) * 8;
    bf16_8 v;
    #pragma unroll
    for (int e = 0; e < 8; ++e) {
        int k = k0 + e;
        float val = 0.f;
        if (k < 25) {
            val = (t == 0) ? m_w[((size_t)n * CIN + c) * 25 + k]
                           : -2.0f * w_w[((size_t)n * CIN + c) * 25 + k];
        }
        v[e] = (__bf16)val;
    }
    *(bf16_8*)(Bp + (size_t)idx * 8) = v;
}

// ---- Layer 1: INRF(3->192, 32x32) + fused 2x2 maxpool -> x00 [64,192,16,16]
// Block: 256 thr = 4 waves = 2 h-rows x 2 half-rows. Grid: 64 img * 16 row-pairs.
__global__ __launch_bounds__(256, 3) void inrf1_mfma(
    const float* __restrict__ x, const __bf16* __restrict__ Bp,
    const float* __restrict__ bias, float* __restrict__ x00)
{
    __shared__ float win[3][6][36];
    __shared__ float hp[192][33];   // half-pooled [n][hl*16+wp], +1 pad vs 32 banks

    const int b  = blockIdx.x >> 4;
    const int h0 = (blockIdx.x & 15) * 2;
    const int tid = threadIdx.x;
    const int wv = tid >> 6, lane = tid & 63;
    const int hl = wv >> 1, half = wv & 1;
    const int mcol = lane & 15, q = lane >> 4;
    const int wpos = half * 16 + mcol;

    for (int i = tid; i < 3 * 6 * 36; i += 256) {
        int c = i / 216, r = (i / 36) % 6, cc = i % 36;
        int gr = h0 + r - 2, gc = cc - 2;
        float v = 0.f;
        if (gr >= 0 && gr < 32 && gc >= 0 && gc < 32)
            v = x[((size_t)(b * 3 + c) * 32 + gr) * 32 + gc];
        win[c][r][cc] = v;
    }
    __syncthreads();

    int offs[8]; bool kok[8];
    #pragma unroll
    for (int e = 0; e < 8; ++e) {
        int k = q * 8 + e;
        kok[e] = (k < 25);
        int kk = kok[e] ? k : 0;
        offs[e] = (hl + kk / 5) * 36 + wpos + (kk % 5);
    }
    const int cen_off = (hl + 2) * 36 + wpos + 2;

    f32x4 acc[NF];
    #pragma unroll
    for (int j = 0; j < NF; ++j) acc[j] = (f32x4){0.f, 0.f, 0.f, 0.f};

    const float* winf = &win[0][0][0];
    for (int c = 0; c < 3; ++c) {
        const float* wf = winf + c * 216;
        float cen = wf[cen_off];
        float vv[8];
        bf16_8 av, as_;
        #pragma unroll
        for (int e = 0; e < 8; ++e) {
            float v = wf[offs[e]];
            vv[e] = kok[e] ? v : 0.f;
            av[e] = (__bf16)vv[e];
        }
        #pragma unroll
        for (int e = 0; e < 8; ++e) {
            float s = fast_tanh125(vv[e] - cen);
            as_[e] = (__bf16)(kok[e] ? s : 0.f);
        }
        const bf16_8* b0 = (const bf16_8*)Bp + ((size_t)(c * 2 + 0) * NF) * 64 + lane;
        const bf16_8* b1 = b0 + NF * 64;
        #pragma unroll
        for (int j = 0; j < NF; ++j)
            acc[j] = __builtin_amdgcn_mfma_f32_16x16x32_bf16(av, b0[j * 64], acc[j], 0, 0, 0);
        #pragma unroll
        for (int j = 0; j < NF; ++j)
            acc[j] = __builtin_amdgcn_mfma_f32_16x16x32_bf16(as_, b1[j * 64], acc[j], 0, 0, 0);
    }

    // D layout: n = lane&15, m-row (=w within half-row) = q*4+reg. Pool w-pairs in-reg.
    #pragma unroll
    for (int j = 0; j < NF; ++j) {
        int n = j * 16 + mcol;
        hp[n][hl * 16 + half * 8 + q * 2 + 0] = fmaxf(acc[j][0], acc[j][1]);
        hp[n][hl * 16 + half * 8 + q * 2 + 1] = fmaxf(acc[j][2], acc[j][3]);
    }
    __syncthreads();

    const int hpout = h0 >> 1;
    for (int i = tid; i < 192 * 16; i += 256) {
        int n = i >> 4, wp = i & 15;
        float v = fmaxf(hp[n][wp], hp[n][16 + wp]) + bias[n];
        x00[((size_t)(b * COUT + n) * 16 + hpout) * 16 + wp] = v;
    }
}

// ---- Layers 2/3: INRF(192->192) via MFMA.
// Block: 512 thr = 8 waves = 4 m-tiles(16 pos) x 2 n-halves(96 ch). B staged in LDS.
template<int H, int W, int KSPLIT>
__global__ __launch_bounds__(512, 2) void inrf_mfma(
    const float* __restrict__ xin, const __bf16* __restrict__ Bp,
    const float* __restrict__ bias, float* __restrict__ out)
{
    constexpr int TR = 16 / W;          // h-rows per m-tile
    constexpr int TRB = 64 / W;         // h-rows per block
    constexpr int HR = TRB + 4, WC = W + 4;
    constexpr int MBLOCKS = (H * W) / 64;
    constexpr int CPS = COUT / KSPLIT;
    constexpr int CG = 2;
    constexpr int ROUNDS = CPS / CG;

    __shared__ __align__(16) __bf16 Bs[CG * 2 * NF * 64 * 8];   // 48 KiB
    __shared__ float win[CG * HR * WC];

    const int per = MBLOCKS * KSPLIT;
    const int b = blockIdx.x / per;
    const int rem = blockIdx.x % per;
    const int mblk = rem % MBLOCKS;
    const int ks = rem / MBLOCKS;
    const int hb = mblk * TRB;

    const int tid = threadIdx.x;
    const int wv = tid >> 6, lane = tid & 63;
    const int mt = wv & 3, nhalf = wv >> 2;
    const int mcol = lane & 15, q = lane >> 4;
    const int mh = mcol / W, mw = mcol % W;
    const int baseRow = mt * TR + mh;

    int offs[8]; bool kok[8];
    #pragma unroll
    for (int e = 0; e < 8; ++e) {
        int k = q * 8 + e;
        kok[e] = (k < 25);
        int kk = kok[e] ? k : 0;
        offs[e] = (baseRow + kk / 5) * WC + mw + (kk % 5);
    }
    const int cen_off = (baseRow + 2) * WC + mw + 2;

    f32x4 acc[6];
    #pragma unroll
    for (int j = 0; j < 6; ++j) acc[j] = (f32x4){0.f, 0.f, 0.f, 0.f};

    for (int rnd = 0; rnd < ROUNDS; ++rnd) {
        const int c0 = ks * CPS + rnd * CG;
        {   // stage B: frag-ordered, pure linear copy -> conflict-free
            const uint4* gsrc = (const uint4*)(Bp + (size_t)c0 * 2 * NF * 64 * 8);
            uint4* ldst = (uint4*)Bs;
            #pragma unroll
            for (int i = 0; i < (CG * 2 * NF * 64) / 512; ++i)
                ldst[i * 512 + tid] = gsrc[i * 512 + tid];
        }
        for (int i = tid; i < CG * HR * WC; i += 512) {
            int cg = i / (HR * WC);
            int r = (i / WC) % HR, cc = i % WC;
            int gr = hb + r - 2, gc = cc - 2;
            float v = 0.f;
            if (gr >= 0 && gr < H && gc >= 0 && gc < W)
                v = xin[((size_t)(b * COUT + c0 + cg) * H + gr) * W + gc];
            win[i] = v;
        }
        __syncthreads();

        #pragma unroll
        for (int cg = 0; cg < CG; ++cg) {
            const float* wf = win + cg * HR * WC;
            float cen = wf[cen_off];
            float vv[8];
            bf16_8 av, as_;
            #pragma unroll
            for (int e = 0; e < 8; ++e) {
                float v = wf[offs[e]];
                vv[e] = kok[e] ? v : 0.f;
                av[e] = (__bf16)vv[e];
            }
            #pragma unroll
            for (int e = 0; e < 8; ++e) {
                float s = fast_tanh125(vv[e] - cen);
                as_[e] = (__bf16)(kok[e] ? s : 0.f);
            }
            const bf16_8* b0 = (const bf16_8*)Bs + ((cg * 2 + 0) * NF + nhalf * 6) * 64 + lane;
            const bf16_8* b1 = b0 + NF * 64;
            #pragma unroll
            for (int j = 0; j < 6; ++j)
                acc[j] = __builtin_amdgcn_mfma_f32_16x16x32_bf16(av, b0[j * 64], acc[j], 0, 0, 0);
            #pragma unroll
            for (int j = 0; j < 6; ++j)
                acc[j] = __builtin_amdgcn_mfma_f32_16x16x32_bf16(as_, b1[j * 64], acc[j], 0, 0, 0);
        }
        __syncthreads();
    }

    // epilogue: D n = lane&15 (+nf*16), m-row = q*4+reg
    const int mrow0 = q * 4;
    const int hlocal = mrow0 / W;
    const int w0 = mrow0 % W;
    const int h = hb + mt * TR + hlocal;
    #pragma unroll
    for (int j = 0; j < 6; ++j) {
        int n = (nhalf * 6 + j) * 16 + mcol;
        f32x4 r = acc[j];
        if constexpr (KSPLIT == 1) {
            float bv = bias[n];
            r[0] += bv; r[1] += bv; r[2] += bv; r[3] += bv;
            *(f32x4*)&out[((size_t)(b * COUT + n) * H + h) * W + w0] = r;
        } else {
            *(f32x4*)&out[(size_t)ks * ((size_t)64 * COUT * H * W) +
                          ((size_t)(b * COUT + n) * H + h) * W + w0] = r;
        }
    }
}

// ---- K-split reduce for layer 3: x04 = sum(part[0..3]) + bias
__global__ void reduce4(const float* __restrict__ part, const float* __restrict__ bias,
                        float* __restrict__ x04) {
    int idx = blockIdx.x * 256 + threadIdx.x;
    if (idx >= 786432) return;
    int n = (idx >> 6) % COUT;
    float s = part[idx] + part[786432 + idx] + part[2 * 786432 + idx] + part[3 * 786432 + idx];
    x04[idx] = s + bias[n];
}

// ---- 2x2 maxpool (x01 -> x03)
__global__ void maxpool2_kernel(const float* __restrict__ in, float* __restrict__ out,
                                int Hout, int Wout, int total) {
    int idx = blockIdx.x * 256 + threadIdx.x;
    if (idx >= total) return;
    int w  = idx % Wout;
    int h  = (idx / Wout) % Hout;
    int bc = idx / (Wout * Hout);
    const float* p = in + ((size_t)bc * Hout * 2 + h * 2) * (Wout * 2) + w * 2;
    int s = Wout * 2;
    out[idx] = fmaxf(fmaxf(p[0], p[1]), fmaxf(p[s], p[s + 1]));
}

// ---- avgpool8 + FC
__global__ void avgfc_kernel(const float* __restrict__ x04, const float* __restrict__ fc_w,
                             const float* __restrict__ fc_b, float* __restrict__ logits) {
    __shared__ float feat[COUT];
    int b = blockIdx.x;
    int t = threadIdx.x;
    if (t < COUT) {
        const float* p = x04 + ((size_t)b * COUT + t) * 64;
        float s = 0.f;
        #pragma unroll
        for (int i = 0; i < 64; ++i) s += p[i];
        feat[t] = s * (1.f / 64.f);
    }
    __syncthreads();
    if (t < 10) {
        float s = fc_b[t];
        #pragma unroll 8
        for (int c = 0; c < COUT; ++c) s = fmaf(fc_w[t * COUT + c], feat[c], s);
        logits[(size_t)b * 10 + t] = s;
    }
}

extern "C" void kernel_launch(void* const* d_in, const int* in_sizes, int n_in,
                              void* d_out, int out_size, void* d_ws, size_t ws_size,
                              hipStream_t stream) {
    const float* x    = (const float*)d_in[0];
    const float* m1_w = (const float*)d_in[1];
    const float* m1_b = (const float*)d_in[2];
    const float* w1_w = (const float*)d_in[3];
    const float* m2_w = (const float*)d_in[4];
    const float* m2_b = (const float*)d_in[5];
    const float* w2_w = (const float*)d_in[6];
    const float* m3_w = (const float*)d_in[7];
    const float* m3_b = (const float*)d_in[8];
    const float* w3_w = (const float*)d_in[9];
    const float* fc_w = (const float*)d_in[10];
    const float* fc_b = (const float*)d_in[11];

    float* out = (float*)d_out;
    float* ws  = (float*)d_ws;

    // d_out: [logits(640) | x00(3145728) | x01(3145728)]
    float* logits = out;
    float* x00 = out + 640;
    float* x01 = out + 640 + 3145728;

    // ws (float units):
    __bf16* Bp1 = (__bf16*)(ws);                 //    36,864 bf16 (18,432 f)
    __bf16* Bp2 = (__bf16*)(ws + 18432);         // 2,359,296 bf16
    __bf16* Bp3 = (__bf16*)(ws + 1198080);       // 2,359,296 bf16
    float* x03   = ws + 2377728;                 //   786,432
    float* x04   = ws + 3164160;                 //   786,432
    float* part3 = ws + 3950592;                 // 3,145,728 (4 splits)

    prep_w<3>  <<<(3   * 2 * NF * 64 + 255) / 256, 256, 0, stream>>>(m1_w, w1_w, Bp1);
    prep_w<192><<<(192 * 2 * NF * 64 + 255) / 256, 256, 0, stream>>>(m2_w, w2_w, Bp2);
    prep_w<192><<<(192 * 2 * NF * 64 + 255) / 256, 256, 0, stream>>>(m3_w, w3_w, Bp3);

    inrf1_mfma<<<64 * 16, 256, 0, stream>>>(x, Bp1, m1_b, x00);
    inrf_mfma<16, 16, 1><<<64 * 4, 512, 0, stream>>>(x00, Bp2, m2_b, x01);
    maxpool2_kernel<<<(786432 + 255) / 256, 256, 0, stream>>>(x01, x03, 8, 8, 786432);
    inrf_mfma<8, 8, 4><<<64 * 4, 512, 0, stream>>>(x03, Bp3, m3_b, part3);
    reduce4<<<(786432 + 255) / 256, 256, 0, stream>>>(part3, m3_b, x04);
    avgfc_kernel<<<64, 256, 0, stream>>>(x04, fc_w, fc_b, logits);
}